// Round 5
// baseline (272.649 us; speedup 1.0000x reference)
//
#include <hip/hip_runtime.h>
#include <hip/hip_fp16.h>
#include <math.h>

#define NE 16
#define HD 1024
#define FD 2048
#define TWO_F 4096

typedef _Float16 half8 __attribute__((ext_vector_type(8)));
typedef float f32x4 __attribute__((ext_vector_type(4)));

// ws layout (4-byte units)
#define TOPI_OFF 0          // 256 int
#define TOPW_OFF 256        // 256 float
#define CNT_OFF  512        // 16 int
#define PREF_OFF 528        // 16 int
#define SLOT_OFF 544        // 256 int (pair -> slot)
#define INVT_OFF 800        // 256 int (slot -> token)
#define XG_OFF   4096       // 256*1024 fp16 = 131072 ints
#define HBUF_OFF (XG_OFF + 131072)    // 256*2048 fp16 = 262144 ints
#define YBUF_OFF (HBUF_OFF + 262144)  // 256*1024 f32

// fp4 e2m1 nibble -> fp16 bits (unscaled)
__device__ __forceinline__ int fp4h(int nib) {
    int c = nib & 7;
    int v;
    if (c == 0) v = 0;
    else if (c == 1) v = 14 << 10;                        // 0.5
    else v = (((c >> 1) + 14) << 10) | ((c & 1) << 9);    // 2^(e-1)*(1+m/2)
    v |= (nib & 8) << 12;                                 // sign
    return v;
}

// LUT byte -> 2 packed fp16, multiplied by packed power-of-2 scale (exact)
__device__ __forceinline__ int declut(const int* lut, int raw, int scl2) {
    int l = lut[raw & 255];
    __half2 p = *reinterpret_cast<const __half2*>(&l);
    __half2 sc = *reinterpret_cast<const __half2*>(&scl2);
    __half2 r = __hmul2(p, sc);
    return *reinterpret_cast<int*>(&r);
}

__global__ void routing_kernel(const float* __restrict__ x, const float* __restrict__ rw,
                               int* __restrict__ top_idx, float* __restrict__ top_w) {
    int t = blockIdx.x;
    int tid = threadIdx.x;          // 256
    int e = tid >> 4, seg = tid & 15;
    const float* xr = x + t * HD + seg * 64;
    const float* wr = rw + e * HD + seg * 64;
    float p = 0.f;
    #pragma unroll 8
    for (int i = 0; i < 64; ++i) p += xr[i] * wr[i];
    __shared__ float part[16][16];
    __shared__ float logit[16];
    part[e][seg] = p;
    __syncthreads();
    if (tid < 16) {
        float s = 0.f;
        #pragma unroll
        for (int i = 0; i < 16; ++i) s += part[tid][i];
        logit[tid] = s;
    }
    __syncthreads();
    if (tid == 0) {
        int i0 = 0; float v0 = logit[0];
        #pragma unroll
        for (int i = 1; i < 16; ++i) { if (logit[i] > v0) { v0 = logit[i]; i0 = i; } }
        int i1 = -1; float v1 = -1e30f;
        #pragma unroll
        for (int i = 0; i < 16; ++i) { if (i != i0 && logit[i] > v1) { v1 = logit[i]; i1 = i; } }
        float w0 = 1.f / (1.f + expf(v1 - v0));
        float w1 = 1.f / (1.f + expf(v0 - v1));
        top_idx[t * 2]     = i0;  top_w[t * 2]     = w0;
        top_idx[t * 2 + 1] = i1;  top_w[t * 2 + 1] = w1;
    }
}

// 256 threads, one per (token, k) pair. Slot order within an expert is arbitrary
// (atomics) but the per-pair computation is order-independent -> output deterministic.
__global__ void build_kernel(const int* __restrict__ top_idx,
                             int* __restrict__ cnt, int* __restrict__ pref,
                             int* __restrict__ slot, int* __restrict__ invtok) {
    __shared__ int scnt[16], spref[16], scur[16];
    int tid = threadIdx.x;
    if (tid < 16) scnt[tid] = 0;
    __syncthreads();
    int e = top_idx[tid];
    atomicAdd(&scnt[e], 1);
    __syncthreads();
    if (tid == 0) {
        int s = 0;
        for (int i = 0; i < 16; ++i) { spref[i] = s; pref[i] = s; cnt[i] = scnt[i]; s += scnt[i]; }
    }
    if (tid < 16) scur[tid] = 0;
    __syncthreads();
    int pos = spref[e] + atomicAdd(&scur[e], 1);
    slot[tid] = pos;
    invtok[pos] = tid >> 1;
}

__global__ void gather_kernel(const float* __restrict__ x, const int* __restrict__ invtok,
                              _Float16* __restrict__ xg) {
    int slt = blockIdx.x;           // 256
    int t = invtok[slt];
    int i = threadIdx.x;            // 256 threads x 4 elems
    float4 v = ((const float4*)(x + (long)t * HD))[i];
    union { _Float16 h[4]; int2 p; } o;
    o.h[0] = (_Float16)v.x; o.h[1] = (_Float16)v.y;
    o.h[2] = (_Float16)v.z; o.h[3] = (_Float16)v.w;
    ((int2*)(xg + (long)slt * HD))[i] = o.p;
}

// gu GEMM + SwiGLU via 16x16x32 f16 MFMA. Block: (e, mtile, fb); wave owns f-tile fb*4+wave.
// B-frag: lane col=lane&15 -> weight row; k-slice (lane>>4)*8 -> one int4 of packed fp4/step.
__global__ __launch_bounds__(256, 4) void gemm1_mfma(
    const _Float16* __restrict__ xg, const int* __restrict__ qblk,
    const int* __restrict__ qscl, const float* __restrict__ bias,
    const int* __restrict__ cnt, const int* __restrict__ pref,
    _Float16* __restrict__ hbuf) {
    int e = blockIdx.x >> 8;
    int mt = (blockIdx.x >> 5) & 7;
    int fb = blockIdx.x & 31;
    int n = cnt[e];
    if (mt * 16 >= n) return;
    __shared__ int lut[256];
    int tid = threadIdx.x;
    lut[tid] = fp4h(tid & 15) | (fp4h(tid >> 4) << 16);
    __syncthreads();
    int wave = tid >> 6, lane = tid & 63;
    int ft = fb * 4 + wave;
    int col = lane & 15;
    int kb = lane >> 4;
    long rg = (long)e * TWO_F + ft * 16 + col;    // gate row
    long ru = rg + FD;                            // up row
    const int4* bg_p = (const int4*)(qblk + rg * 512) + kb;
    const int4* bu_p = (const int4*)(qblk + ru * 512) + kb;
    const int* sg_p = qscl + rg * 32;
    const int* su_p = qscl + ru * 32;
    int base = pref[e];
    int arow = base + mt * 16 + col;              // ragged rows: computed, never stored
    if (arow > 255) arow = 255;
    const _Float16* ax = xg + (long)arow * HD + kb * 8;

    f32x4 accg = {0.f, 0.f, 0.f, 0.f}, accu = {0.f, 0.f, 0.f, 0.f};
    for (int s = 0; s < 32; ++s) {
        half8 a = *(const half8*)(ax + 32 * s);
        int4 bgq = bg_p[s * 4];
        int4 buq = bu_p[s * 4];
        int sg = (sg_p[s] - 112) << 10; sg |= sg << 16;   // 2^(s-127) as packed fp16
        int su = (su_p[s] - 112) << 10; su |= su << 16;
        union { int i[4]; half8 h; } g, u;
        g.i[0] = declut(lut, bgq.x, sg); g.i[1] = declut(lut, bgq.y, sg);
        g.i[2] = declut(lut, bgq.z, sg); g.i[3] = declut(lut, bgq.w, sg);
        u.i[0] = declut(lut, buq.x, su); u.i[1] = declut(lut, buq.y, su);
        u.i[2] = declut(lut, buq.z, su); u.i[3] = declut(lut, buq.w, su);
        accg = __builtin_amdgcn_mfma_f32_16x16x32_f16(a, g.h, accg, 0, 0, 0);
        accu = __builtin_amdgcn_mfma_f32_16x16x32_f16(a, u.h, accu, 0, 0, 0);
    }
    int f = ft * 16 + col;
    float bg = bias[(long)e * TWO_F + f];
    float bu = bias[(long)e * TWO_F + FD + f];
    #pragma unroll
    for (int r = 0; r < 4; ++r) {
        int row = mt * 16 + kb * 4 + r;           // D: col=lane&15, row=(lane>>4)*4+reg
        if (row < n) {
            float gg = accg[r] + bg;
            float uu = accu[r] + bu;
            float h = (gg / (1.f + expf(-gg))) * uu;
            hbuf[(long)(base + row) * FD + f] = (_Float16)(h * 0.0625f);  // 2^-4, exact shift
        }
    }
}

// down GEMM via MFMA. K=2048 (64 steps). y = 16*acc + bias.
__global__ __launch_bounds__(256, 4) void gemm2_mfma(
    const _Float16* __restrict__ hbuf, const int* __restrict__ qblk,
    const int* __restrict__ qscl, const float* __restrict__ bias,
    const int* __restrict__ cnt, const int* __restrict__ pref,
    float* __restrict__ ybuf) {
    int e = blockIdx.x >> 7;
    int mt = (blockIdx.x >> 4) & 7;
    int hb = blockIdx.x & 15;
    int n = cnt[e];
    if (mt * 16 >= n) return;
    __shared__ int lut[256];
    int tid = threadIdx.x;
    lut[tid] = fp4h(tid & 15) | (fp4h(tid >> 4) << 16);
    __syncthreads();
    int wave = tid >> 6, lane = tid & 63;
    int ht = hb * 4 + wave;
    int col = lane & 15;
    int kb = lane >> 4;
    long r = (long)e * HD + ht * 16 + col;
    const int4* b_p = (const int4*)(qblk + r * 1024) + kb;
    const int* s_p = qscl + r * 64;
    int base = pref[e];
    int arow = base + mt * 16 + col;
    if (arow > 255) arow = 255;
    const _Float16* ax = hbuf + (long)arow * FD + kb * 8;

    f32x4 acc = {0.f, 0.f, 0.f, 0.f};
    for (int s = 0; s < 64; ++s) {
        half8 a = *(const half8*)(ax + 32 * s);
        int4 bq = b_p[s * 4];
        int sc = (s_p[s] - 112) << 10; sc |= sc << 16;
        union { int i[4]; half8 h; } w;
        w.i[0] = declut(lut, bq.x, sc); w.i[1] = declut(lut, bq.y, sc);
        w.i[2] = declut(lut, bq.z, sc); w.i[3] = declut(lut, bq.w, sc);
        acc = __builtin_amdgcn_mfma_f32_16x16x32_f16(a, w.h, acc, 0, 0, 0);
    }
    int hcol = ht * 16 + col;
    float bv = bias[(long)e * HD + hcol];
    #pragma unroll
    for (int rr = 0; rr < 4; ++rr) {
        int row = mt * 16 + kb * 4 + rr;
        if (row < n) {
            ybuf[(long)(base + row) * HD + hcol] = acc[rr] * 16.f + bv;
        }
    }
}

__global__ void combine_kernel(const float* __restrict__ ybuf, const int* __restrict__ slot,
                               const float* __restrict__ topw, float* __restrict__ out) {
    int t = blockIdx.x;
    int i = threadIdx.x;   // 256, float4 each
    int s0 = slot[2 * t], s1 = slot[2 * t + 1];
    float w0 = topw[2 * t], w1 = topw[2 * t + 1];
    float4 a = ((const float4*)(ybuf + (long)s0 * HD))[i];
    float4 b = ((const float4*)(ybuf + (long)s1 * HD))[i];
    float4 o;
    o.x = w0 * a.x + w1 * b.x;
    o.y = w0 * a.y + w1 * b.y;
    o.z = w0 * a.z + w1 * b.z;
    o.w = w0 * a.w + w1 * b.w;
    ((float4*)(out + (long)t * HD))[i] = o;
}

extern "C" void kernel_launch(void* const* d_in, const int* in_sizes, int n_in,
                              void* d_out, int out_size, void* d_ws, size_t ws_size,
                              hipStream_t stream) {
    const float* x          = (const float*)d_in[0];
    const float* rw         = (const float*)d_in[1];
    const float* bias_gu    = (const float*)d_in[2];
    const float* bias_down  = (const float*)d_in[3];
    const int*   blocks_gu  = (const int*)d_in[4];
    const int*   scales_gu  = (const int*)d_in[5];
    const int*   blocks_down= (const int*)d_in[6];
    const int*   scales_down= (const int*)d_in[7];
    float* out = (float*)d_out;
    int*   wsI = (int*)d_ws;
    float* wsF = (float*)d_ws;
    _Float16* xg   = (_Float16*)(wsI + XG_OFF);
    _Float16* hbuf = (_Float16*)(wsI + HBUF_OFF);
    float*    ybuf = wsF + YBUF_OFF;

    routing_kernel<<<128, 256, 0, stream>>>(x, rw, wsI + TOPI_OFF, wsF + TOPW_OFF);
    build_kernel<<<1, 256, 0, stream>>>(wsI + TOPI_OFF, wsI + CNT_OFF, wsI + PREF_OFF,
                                        wsI + SLOT_OFF, wsI + INVT_OFF);
    gather_kernel<<<256, 256, 0, stream>>>(x, wsI + INVT_OFF, xg);
    gemm1_mfma<<<NE * 8 * 32, 256, 0, stream>>>(xg, blocks_gu, scales_gu, bias_gu,
                                                wsI + CNT_OFF, wsI + PREF_OFF, hbuf);
    gemm2_mfma<<<NE * 8 * 16, 256, 0, stream>>>(hbuf, blocks_down, scales_down, bias_down,
                                                wsI + CNT_OFF, wsI + PREF_OFF, ybuf);
    combine_kernel<<<128, 256, 0, stream>>>(ybuf, wsI + SLOT_OFF, wsF + TOPW_OFF, out);
}